// Round 1
// baseline (2334.542 us; speedup 1.0000x reference)
//
#include <hip/hip_runtime.h>
#include <cstdint>
#include <cstddef>

namespace {

constexpr int T_DIM = 8192;   // tokens
constexpr int D_DIM = 4096;   // d_in (K)
constexpr int U_DIM = 16384;  // units (N)

typedef float f32x4 __attribute__((ext_vector_type(4)));

__device__ __forceinline__ void gl_lds16(const void* g, void* l) {
  typedef const __attribute__((address_space(1))) unsigned int* gp_t;
  typedef __attribute__((address_space(3))) unsigned int* lp_t;
  __builtin_amdgcn_global_load_lds((gp_t)g, (lp_t)l, 16, 0, 0);
}

// ---------------- amax reduction (float bits atomicMax; all values >= 0) ----
__global__ void amax_kernel(const float4* __restrict__ p, int n4,
                            unsigned* __restrict__ out) {
  float m = 0.f;
  const int stride = gridDim.x * blockDim.x;
  for (int i = blockIdx.x * blockDim.x + threadIdx.x; i < n4; i += stride) {
    float4 v = p[i];
    m = fmaxf(m, fmaxf(fmaxf(fabsf(v.x), fabsf(v.y)),
                       fmaxf(fabsf(v.z), fabsf(v.w))));
  }
#pragma unroll
  for (int off = 32; off > 0; off >>= 1)
    m = fmaxf(m, __shfl_down(m, off, 64));
  if ((threadIdx.x & 63) == 0) atomicMax(out, __float_as_uint(m));
}

// ---------------- quantize x: f32 [T][D] -> fp8 [T][D] ---------------------
__global__ void quant_x_kernel(const float4* __restrict__ x,
                               unsigned* __restrict__ xq, int n4,
                               const unsigned* __restrict__ amax_bits) {
  const float s = 448.f / fmaxf(__uint_as_float(amax_bits[0]), 1e-12f);
  const int stride = gridDim.x * blockDim.x;
  for (int i = blockIdx.x * blockDim.x + threadIdx.x; i < n4; i += stride) {
    float4 v = x[i];
    int pk = 0;
    pk = __builtin_amdgcn_cvt_pk_fp8_f32(v.x * s, v.y * s, pk, false);
    pk = __builtin_amdgcn_cvt_pk_fp8_f32(v.z * s, v.w * s, pk, true);
    xq[i] = (unsigned)pk;
  }
}

// ------- quantize + transpose kernel: f32 [D][U] -> fp8 [U][D] -------------
__global__ void quant_kT_kernel(const float* __restrict__ k,
                                unsigned char* __restrict__ kq,
                                const unsigned* __restrict__ amax_bits) {
  __shared__ float smf[64 * 65];  // [u_local][d_local], pad to break banks
  const float s = 448.f / fmaxf(__uint_as_float(amax_bits[1]), 1e-12f);
  const int u0 = blockIdx.x * 64, d0 = blockIdx.y * 64;
  const int t = threadIdx.x;
  const int r0 = t >> 4, c4 = (t & 15) << 2;
#pragma unroll
  for (int rr = r0; rr < 64; rr += 16) {
    float4 v = *(const float4*)(k + (size_t)(d0 + rr) * U_DIM + u0 + c4);
    smf[(c4 + 0) * 65 + rr] = v.x;
    smf[(c4 + 1) * 65 + rr] = v.y;
    smf[(c4 + 2) * 65 + rr] = v.z;
    smf[(c4 + 3) * 65 + rr] = v.w;
  }
  __syncthreads();
#pragma unroll
  for (int rr = r0; rr < 64; rr += 16) {
    float a = smf[rr * 65 + c4 + 0];
    float b = smf[rr * 65 + c4 + 1];
    float c = smf[rr * 65 + c4 + 2];
    float d = smf[rr * 65 + c4 + 3];
    int pk = 0;
    pk = __builtin_amdgcn_cvt_pk_fp8_f32(a * s, b * s, pk, false);
    pk = __builtin_amdgcn_cvt_pk_fp8_f32(c * s, d * s, pk, true);
    *(unsigned*)(kq + (size_t)(u0 + rr) * D_DIM + d0 + c4) = (unsigned)pk;
  }
}

// ---------------- fp8 GEMM + dequant + bias + gelu -------------------------
// A: fp8 [T][D] row-major.  B: fp8 [U][D] row-major (pre-transposed kernel).
// 128x128 block tile, BK=64, 2x2 waves, each wave 4x4 of 16x16x32 MFMA.
__global__ __launch_bounds__(256) void gemm_fp8_kernel(
    const unsigned char* __restrict__ A, const unsigned char* __restrict__ B,
    const float* __restrict__ bias, const unsigned* __restrict__ amax_bits,
    float* __restrict__ out) {
  __shared__ unsigned char As[128 * 64];
  __shared__ unsigned char Bs[128 * 64];

  const int tid = threadIdx.x;
  const int lane = tid & 63;
  const int wave = tid >> 6;
  const int wr = wave >> 1, wc = wave & 1;
  const size_t m0 = (size_t)blockIdx.y * 128;
  const size_t n0 = (size_t)blockIdx.x * 128;

  const float sx = 448.f / fmaxf(__uint_as_float(amax_bits[0]), 1e-12f);
  const float sk = 448.f / fmaxf(__uint_as_float(amax_bits[1]), 1e-12f);
  const float inv_s = 1.f / (sx * sk);

  // Staging: 512 chunks of 16B per tile; LDS slot ci = it*256 + tid holds
  // global chunk col c = (ci&3) ^ (row&3)  (XOR swizzle, applied on the
  // GLOBAL side since global_load_lds LDS dest is wave-uniform + lane*16).
  const int srow = tid >> 2;                        // 0..63 (it adds +64)
  const int scol = (((tid & 3) ^ (srow & 3)) << 4); // row&3 invariant under +64
  const unsigned char* gA0 = A + (m0 + srow) * D_DIM + scol;
  const unsigned char* gA1 = gA0 + (size_t)64 * D_DIM;
  const unsigned char* gB0 = B + (n0 + srow) * D_DIM + scol;
  const unsigned char* gB1 = gB0 + (size_t)64 * D_DIM;
  unsigned char* lA0 = As + tid * 16;
  unsigned char* lA1 = As + 4096 + tid * 16;
  unsigned char* lB0 = Bs + tid * 16;
  unsigned char* lB1 = Bs + 4096 + tid * 16;

  // Fragment reads: A[m][k], m = wrow*64+i*16+(lane&15), k = (lane>>4)*8+j
  // (+ s*32). Chunk col cglob = s*2 + (quad>>1), swizzled by lane&3 (== m&3).
  const int lane15 = lane & 15;
  const int koff0 =
      ((((lane >> 5) ^ (lane & 3)) << 4) | (((lane >> 4) & 1) << 3));
  const unsigned char* arow = As + (wr * 64 + lane15) * 64;
  const unsigned char* brow = Bs + (wc * 64 + lane15) * 64;

  f32x4 acc[4][4];
#pragma unroll
  for (int i = 0; i < 4; ++i)
#pragma unroll
    for (int j = 0; j < 4; ++j) acc[i][j] = (f32x4){0.f, 0.f, 0.f, 0.f};

  for (int kt = 0; kt < D_DIM; kt += 64) {
    __syncthreads();  // previous iteration's LDS reads done
    gl_lds16(gA0 + kt, lA0);
    gl_lds16(gA1 + kt, lA1);
    gl_lds16(gB0 + kt, lB0);
    gl_lds16(gB1 + kt, lB1);
    __syncthreads();  // staging complete (compiler drains vmcnt)
#pragma unroll
    for (int s = 0; s < 2; ++s) {
      const int ko = koff0 ^ (s << 5);
      long long a0 = *(const long long*)(arow + ko);
      long long a1 = *(const long long*)(arow + 1024 + ko);
      long long a2 = *(const long long*)(arow + 2048 + ko);
      long long a3 = *(const long long*)(arow + 3072 + ko);
      long long b0 = *(const long long*)(brow + ko);
      long long b1 = *(const long long*)(brow + 1024 + ko);
      long long b2 = *(const long long*)(brow + 2048 + ko);
      long long b3 = *(const long long*)(brow + 3072 + ko);
      acc[0][0] = __builtin_amdgcn_mfma_f32_16x16x32_fp8_fp8(a0, b0, acc[0][0], 0, 0, 0);
      acc[0][1] = __builtin_amdgcn_mfma_f32_16x16x32_fp8_fp8(a0, b1, acc[0][1], 0, 0, 0);
      acc[0][2] = __builtin_amdgcn_mfma_f32_16x16x32_fp8_fp8(a0, b2, acc[0][2], 0, 0, 0);
      acc[0][3] = __builtin_amdgcn_mfma_f32_16x16x32_fp8_fp8(a0, b3, acc[0][3], 0, 0, 0);
      acc[1][0] = __builtin_amdgcn_mfma_f32_16x16x32_fp8_fp8(a1, b0, acc[1][0], 0, 0, 0);
      acc[1][1] = __builtin_amdgcn_mfma_f32_16x16x32_fp8_fp8(a1, b1, acc[1][1], 0, 0, 0);
      acc[1][2] = __builtin_amdgcn_mfma_f32_16x16x32_fp8_fp8(a1, b2, acc[1][2], 0, 0, 0);
      acc[1][3] = __builtin_amdgcn_mfma_f32_16x16x32_fp8_fp8(a1, b3, acc[1][3], 0, 0, 0);
      acc[2][0] = __builtin_amdgcn_mfma_f32_16x16x32_fp8_fp8(a2, b0, acc[2][0], 0, 0, 0);
      acc[2][1] = __builtin_amdgcn_mfma_f32_16x16x32_fp8_fp8(a2, b1, acc[2][1], 0, 0, 0);
      acc[2][2] = __builtin_amdgcn_mfma_f32_16x16x32_fp8_fp8(a2, b2, acc[2][2], 0, 0, 0);
      acc[2][3] = __builtin_amdgcn_mfma_f32_16x16x32_fp8_fp8(a2, b3, acc[2][3], 0, 0, 0);
      acc[3][0] = __builtin_amdgcn_mfma_f32_16x16x32_fp8_fp8(a3, b0, acc[3][0], 0, 0, 0);
      acc[3][1] = __builtin_amdgcn_mfma_f32_16x16x32_fp8_fp8(a3, b1, acc[3][1], 0, 0, 0);
      acc[3][2] = __builtin_amdgcn_mfma_f32_16x16x32_fp8_fp8(a3, b2, acc[3][2], 0, 0, 0);
      acc[3][3] = __builtin_amdgcn_mfma_f32_16x16x32_fp8_fp8(a3, b3, acc[3][3], 0, 0, 0);
    }
  }

  // Epilogue: C/D layout col=lane&15, row=(lane>>4)*4+r (dtype-independent).
  const int q4 = (lane >> 4) << 2;
  float bj[4];
#pragma unroll
  for (int j = 0; j < 4; ++j)
    bj[j] = bias[n0 + wc * 64 + j * 16 + lane15];

#pragma unroll
  for (int i = 0; i < 4; ++i) {
    const size_t grow_base = m0 + (size_t)(wr * 64 + i * 16 + q4);
#pragma unroll
    for (int r = 0; r < 4; ++r) {
      float* orow = out + (grow_base + r) * U_DIM + n0 + wc * 64 + lane15;
#pragma unroll
      for (int j = 0; j < 4; ++j) {
        float v = acc[i][j][r] * inv_s + bj[j];
        // tanh-approx gelu, overflow-safe tanh form
        float uu = 0.7978845608028654f * (v + 0.044715f * v * v * v);
        float e = __expf(2.f * uu);
        float th = 1.f - 2.f / (e + 1.f);
        orow[j * 16] = 0.5f * v * (1.f + th);
      }
    }
  }
}

}  // namespace

extern "C" void kernel_launch(void* const* d_in, const int* in_sizes, int n_in,
                              void* d_out, int out_size, void* d_ws,
                              size_t ws_size, hipStream_t stream) {
  const float* x = (const float*)d_in[0];
  const float* kern = (const float*)d_in[1];
  const float* bias = (const float*)d_in[2];
  float* out = (float*)d_out;

  unsigned char* ws = (unsigned char*)d_ws;
  unsigned* amax_bits = (unsigned*)ws;  // [0]=amax(x) bits, [1]=amax(kernel)
  unsigned char* xq = ws + 256;                                  // 32 MB
  unsigned char* kqt = ws + 256 + (size_t)T_DIM * D_DIM;         // 64 MB

  // ws is poisoned 0xAA before every call — zero the amax accumulators.
  hipMemsetAsync(d_ws, 0, 8, stream);

  amax_kernel<<<2048, 256, 0, stream>>>((const float4*)x, T_DIM * D_DIM / 4,
                                        amax_bits + 0);
  amax_kernel<<<4096, 256, 0, stream>>>((const float4*)kern, D_DIM * U_DIM / 4,
                                        amax_bits + 1);
  quant_x_kernel<<<2048, 256, 0, stream>>>((const float4*)x, (unsigned*)xq,
                                           T_DIM * D_DIM / 4, amax_bits);
  quant_kT_kernel<<<dim3(U_DIM / 64, D_DIM / 64), 256, 0, stream>>>(
      kern, kqt, amax_bits);
  gemm_fp8_kernel<<<dim3(U_DIM / 128, T_DIM / 128), 256, 0, stream>>>(
      xq, kqt, bias, amax_bits, out);
}